// Round 4
// baseline (470.532 us; speedup 1.0000x reference)
//
#include <hip/hip_runtime.h>
#include <hip/hip_bf16.h>

#define EDGES 600000
#define DIN 128
#define DHID 256
#define DOUT 128

#define NCHUNK 37500            // EDGES / 16 (exact, no tail)
#define NBLK 256                // 1 block per CU, single round
#define THREADS 768             // 12 waves/block -> 3 waves/SIMD
#define NWAVES 3072             // NBLK * 12
#define STRIDE NWAVES

// LDS map (bytes):
//   [0, 65536)        W1 frags  shortx8[(t*4+ks)*64 + lane]
//   [65536, 131072)   W2 frags  shortx4[(t*8+ot)*64 + lane]
//   [131072, 132096)  b1 (256 f32)
//   [132096, 132608)  b2 (128 f32)
#define W2_OFF 65536
#define B1_OFF 131072
#define B2_OFF 132096
#define LDS_BYTES 132608

typedef __attribute__((ext_vector_type(4))) float floatx4;
typedef __attribute__((ext_vector_type(4))) short shortx4;
typedef __attribute__((ext_vector_type(8))) short shortx8;

__device__ inline unsigned short f2bf_rne(float f) {
    union { float f; unsigned u; } v; v.f = f;
    unsigned r = v.u + 0x7FFFu + ((v.u >> 16) & 1u);
    return (unsigned short)(r >> 16);
}

// Pre-pass: convert W1/W2 fp32 -> bf16, swizzled fragment-major.
// W1s: frag (t,ks): 64 lanes x 8 bf16  (A-frag of 16x16x32: m=lane&15, k=q*8+j)
// W2s: frag (t,ot): 64 lanes x 4 bf16  (A-frag of 16x16x16: m=lane&15, k=q*4+j)
__global__ __launch_bounds__(256) void prep_kernel(
        const float* __restrict__ W1, const float* __restrict__ W2,
        unsigned short* __restrict__ ws) {
    int j = blockIdx.x * 256 + threadIdx.x;
    if (j < 4096) {                       // W1 frags: 16 t * 4 ks * 64 lanes
        int lane = j & 63, fs = j >> 6;
        int ks = fs & 3, t = fs >> 2;
        int hid = t * 16 + (lane & 15), q = lane >> 4;
        const float* src = W1 + hid * DIN + ks * 32 + q * 8;
        shortx8 v;
        #pragma unroll
        for (int i = 0; i < 8; ++i) v[i] = (short)f2bf_rne(src[i]);
        *((shortx8*)ws + j) = v;
    } else if (j < 12288) {               // W2 frags: 16 t * 8 ot * 64 lanes
        int j2 = j - 4096;
        int lane = j2 & 63, fs = j2 >> 6;
        int ot = fs & 7, t = fs >> 3;     // layout (t*8+ot)*64+lane
        int o = ot * 16 + (lane & 15), q = lane >> 4;
        const float* src = W2 + o * DHID + t * 16 + q * 4;
        shortx4 v;
        #pragma unroll
        for (int i = 0; i < 4; ++i) v[i] = (short)f2bf_rne(src[i]);
        *((shortx4*)(ws + 32768) + j2) = v;
    }
}

// Gather one 16-edge chunk's B-operand slice directly from x into registers.
// Lane (q,col): edge=col, floats [ks*32 + q*8 .. +7] of both endpoint rows.
#define GATHER(RAW, NA, NB) do {                                              \
    const float* pa_ = x + (size_t)(NA) * DIN + q * 8;                        \
    const float* pb_ = x + (size_t)(NB) * DIN + q * 8;                        \
    _Pragma("unroll")                                                         \
    for (int ks_ = 0; ks_ < 4; ++ks_) {                                       \
        RAW[ks_*4+0] = *(const float4*)(pa_ + ks_*32);                        \
        RAW[ks_*4+1] = *(const float4*)(pa_ + ks_*32 + 4);                    \
        RAW[ks_*4+2] = *(const float4*)(pb_ + ks_*32);                        \
        RAW[ks_*4+3] = *(const float4*)(pb_ + ks_*32 + 4);                    \
    }                                                                         \
} while (0)

// Per-wave pipelined fused kernel (depth-1, single raw buffer -> no spills).
// Each wave owns 16-edge chunks (chunk = gw + k*STRIDE). Per chunk:
//   convert raw -> sfrag; issue next chunk's gather (completes under MFMA);
//   GEMM1 transposed (acc1 = W1frag * sfrag): C col=edge, row=hid-frag;
//   relu+bias+bf16 in regs; GEMM2 transposed (acc2 = W2frag * hfrag):
//   C col=edge, row=outcol-frag -> epilogue is 8 float4 nt-stores per lane.
// Weights+biases live in LDS so the MFMA loop has ZERO vmem ops -> the
// in-flight gather loads are never drained early by vmcnt waits.
__global__ __launch_bounds__(THREADS, 3) void gin_kernel(
        const float* __restrict__ x, const int* __restrict__ ei,
        const float* __restrict__ b1, const float* __restrict__ b2,
        const unsigned short* __restrict__ wsw,
        float* __restrict__ out) {
    extern __shared__ char smem[];
    const int tid = threadIdx.x;
    const int lane = tid & 63, q = lane >> 4, col = lane & 15;

    // ---- prologue ----
    const int gw = blockIdx.x * 12 + (tid >> 6);  // < 3072 <= NCHUNK: valid
    int ch = gw;
    const int e0 = ch * 16 + col;
    const int na0 = ei[e0];
    const int nb0 = ei[EDGES + e0];

    // weights -> LDS (131072 B = 8192 float4)
    {
        const float4* gsrc = (const float4*)wsw;
        for (int idx = tid; idx < 8192; idx += THREADS) {
            float4 v = gsrc[idx];
            *(float4*)(smem + (size_t)idx * 16) = v;
        }
        if (tid < 384) {
            float v = (tid < 256) ? b1[tid] : b2[tid - 256];
            *(float*)(smem + B1_OFF + tid * 4) = v;
        }
    }

    // gather chunk0 into raw regs
    float4 raw[16];
    GATHER(raw, na0, nb0);

    // ei prefetch for chunk1
    int naN, nbN;
    {
        const int e1 = (ch + STRIDE) * 16 + col;
        naN = ei[e1];
        nbN = ei[EDGES + e1];
    }
    __syncthreads();   // weights ready; no barriers after this point

    const shortx8* w1l = (const shortx8*)smem + lane;
    const shortx4* w2l = (const shortx4*)(smem + W2_OFF) + lane;
    const floatx4* b1l = (const floatx4*)(smem + B1_OFF) + q;
    const floatx4* b2l = (const floatx4*)(smem + B2_OFF) + q;

    for (;;) {
        // convert raw -> sfrag (B-frag: n=edge=col, k=ks*32+q*8+j)
        shortx8 sfrag[4];
        #pragma unroll
        for (int ks = 0; ks < 4; ++ks) {
            float4 u0 = raw[ks*4+0], u1 = raw[ks*4+1];
            float4 v0 = raw[ks*4+2], v1 = raw[ks*4+3];
            union { shortx8 s8; __hip_bfloat162 b[4]; } pk;
            pk.b[0] = __float22bfloat162_rn(make_float2(u0.x+v0.x, u0.y+v0.y));
            pk.b[1] = __float22bfloat162_rn(make_float2(u0.z+v0.z, u0.w+v0.w));
            pk.b[2] = __float22bfloat162_rn(make_float2(u1.x+v1.x, u1.y+v1.y));
            pk.b[3] = __float22bfloat162_rn(make_float2(u1.z+v1.z, u1.w+v1.w));
            sfrag[ks] = pk.s8;
        }

        // issue next chunk's gather NOW; it completes under the MFMA phase
        const int chN = ch + STRIDE;
        const bool haveN = (chN < NCHUNK);
        if (haveN) {
            GATHER(raw, naN, nbN);
            const int ch2 = chN + STRIDE;
            if (ch2 < NCHUNK) {
                const int e2 = ch2 * 16 + col;
                naN = ei[e2];
                nbN = ei[EDGES + e2];
            }
        }

        // ---- MFMA phase: LDS-only operand traffic ----
        floatx4 acc2[8];
        #pragma unroll
        for (int ot = 0; ot < 8; ++ot) acc2[ot] = b2l[ot*4];   // bias init

        #pragma unroll 1
        for (int t = 0; t < 16; ++t) {
            shortx8 a1[4];
            #pragma unroll
            for (int ks = 0; ks < 4; ++ks) a1[ks] = w1l[(t*4+ks)*64];
            floatx4 acc1 = b1l[t*4];                            // bias init
            #pragma unroll
            for (int ks = 0; ks < 4; ++ks)
                acc1 = __builtin_amdgcn_mfma_f32_16x16x32_bf16(a1[ks], sfrag[ks], acc1, 0, 0, 0);
            union { shortx4 s4; __hip_bfloat162 b[2]; } pk;
            pk.b[0] = __float22bfloat162_rn(make_float2(fmaxf(acc1[0], 0.f), fmaxf(acc1[1], 0.f)));
            pk.b[1] = __float22bfloat162_rn(make_float2(fmaxf(acc1[2], 0.f), fmaxf(acc1[3], 0.f)));
            const shortx4 hf = pk.s4;
            #pragma unroll
            for (int ot = 0; ot < 8; ++ot) {
                shortx4 wb = w2l[(t*8+ot)*64];
                // swapped operands: D^T, C-layout col=edge, row=outcol-frag
                acc2[ot] = __builtin_amdgcn_mfma_f32_16x16x16bf16_1k(wb, hf, acc2[ot], 0, 0, 0);
            }
        }

        // ---- epilogue: out[edge=ch*16+col][ot*16 + q*4 + r] = 0.5*acc2 ----
        // __builtin_nontemporal_store: compiler-tracked (gets the final
        // s_waitcnt vmcnt(0) before s_endpgm -- the r3 asm store did not,
        // which dropped in-flight stores and failed correctness).
        {
            float* op = out + (size_t)(ch * 16 + col) * DOUT + q * 4;
            #pragma unroll
            for (int ot = 0; ot < 8; ++ot) {
                floatx4 v = acc2[ot] * 0.5f;
                __builtin_nontemporal_store(v, (floatx4*)(op + ot * 16));
            }
        }

        if (!haveN) break;
        ch = chN;
    }
}

extern "C" void kernel_launch(void* const* d_in, const int* in_sizes, int n_in,
                              void* d_out, int out_size, void* d_ws, size_t ws_size,
                              hipStream_t stream) {
    const float* x  = (const float*)d_in[0];
    const int*   ei = (const int*)d_in[1];     // edge_index as int32 per harness
    const float* W1 = (const float*)d_in[2];
    const float* b1 = (const float*)d_in[3];
    const float* W2 = (const float*)d_in[4];
    const float* b2 = (const float*)d_in[5];
    unsigned short* ws = (unsigned short*)d_ws;   // 64KB W1s + 64KB W2s

    static bool attr_done = false;
    if (!attr_done) {
        (void)hipFuncSetAttribute((const void*)gin_kernel,
                                  hipFuncAttributeMaxDynamicSharedMemorySize,
                                  LDS_BYTES);
        attr_done = true;
    }

    prep_kernel<<<48, 256, 0, stream>>>(W1, W2, ws);
    gin_kernel<<<NBLK, THREADS, LDS_BYTES, stream>>>(x, ei, b1, b2, ws, (float*)d_out);
}

// Round 5
// 435.813 us; speedup vs baseline: 1.0797x; 1.0797x over previous
//
#include <hip/hip_runtime.h>
#include <hip/hip_bf16.h>

#define EDGES 600000
#define DIN 128
#define DHID 256
#define DOUT 128
#define NNODES 100000

#define NCHUNK 37500            // EDGES / 16 (exact, no tail)
#define NBLK 256                // 1 block per CU, single round
#define THREADS 768             // 12 waves/block -> 3 waves/SIMD
#define STRIDE 3072             // NBLK * 12 waves

// LDS map (bytes):
//   [0, 65536)        W1 frags  shortx8[(t*4+ks)*64 + lane]
//   [65536, 131072)   W2 frags  shortx4[(t*8+ot)*64 + lane]
//   [131072, 132096)  b1 (256 f32)
//   [132096, 132608)  b2 (128 f32)
#define W2_OFF 65536
#define B1_OFF 131072
#define B2_OFF 132096
#define LDS_BYTES 132608

// ws (shorts): [0,32768) W1 frags, [32768,65536) W2 frags,
//              [65536, 65536+12800000) x in bf16 (25.6 MB, L3-resident)
#define XB_OFF_SHORTS 65536
#define WS_BYTES_NEEDED (131072ull + (unsigned long long)NNODES * DIN * 2ull)

typedef __attribute__((ext_vector_type(4))) float floatx4;
typedef __attribute__((ext_vector_type(4))) short shortx4;
typedef __attribute__((ext_vector_type(8))) short shortx8;

__device__ inline unsigned short f2bf_rne(float f) {
    union { float f; unsigned u; } v; v.f = f;
    unsigned r = v.u + 0x7FFFu + ((v.u >> 16) & 1u);
    return (unsigned short)(r >> 16);
}

// Pre-pass: convert W1/W2 fp32 -> bf16, swizzled fragment-major.
// W1s: frag (t,ks): 64 lanes x 8 bf16  (A-frag of 16x16x32: m=lane&15, k=q*8+j)
// W2s: frag (t,ot): 64 lanes x 4 bf16  (A-frag of 16x16x16: m=lane&15, k=q*4+j)
__global__ __launch_bounds__(256) void prep_kernel(
        const float* __restrict__ W1, const float* __restrict__ W2,
        unsigned short* __restrict__ ws) {
    int j = blockIdx.x * 256 + threadIdx.x;
    if (j < 4096) {                       // W1 frags: 16 t * 4 ks * 64 lanes
        int lane = j & 63, fs = j >> 6;
        int ks = fs & 3, t = fs >> 2;
        int hid = t * 16 + (lane & 15), q = lane >> 4;
        const float* src = W1 + hid * DIN + ks * 32 + q * 8;
        shortx8 v;
        #pragma unroll
        for (int i = 0; i < 8; ++i) v[i] = (short)f2bf_rne(src[i]);
        *((shortx8*)ws + j) = v;
    } else if (j < 12288) {               // W2 frags: 16 t * 8 ot * 64 lanes
        int j2 = j - 4096;
        int lane = j2 & 63, fs = j2 >> 6;
        int ot = fs & 7, t = fs >> 3;     // layout (t*8+ot)*64+lane
        int o = ot * 16 + (lane & 15), q = lane >> 4;
        const float* src = W2 + o * DHID + t * 16 + q * 4;
        shortx4 v;
        #pragma unroll
        for (int i = 0; i < 4; ++i) v[i] = (short)f2bf_rne(src[i]);
        *((shortx4*)(ws + 32768) + j2) = v;
    }
}

// Pre-pass: x fp32 -> bf16 (25.6 MB working set -> gathers become L3 hits
// and read half the bytes).
__global__ __launch_bounds__(256) void prep_x(
        const float* __restrict__ x, unsigned short* __restrict__ xb) {
    const int total = NNODES * DIN / 4;   // 3.2M float4
    for (int i = blockIdx.x * 256 + threadIdx.x; i < total; i += gridDim.x * 256) {
        float4 v = ((const float4*)x)[i];
        shortx4 o;
        o[0] = (short)f2bf_rne(v.x); o[1] = (short)f2bf_rne(v.y);
        o[2] = (short)f2bf_rne(v.z); o[3] = (short)f2bf_rne(v.w);
        *((shortx4*)xb + i) = o;
    }
}

// Per-wave pipelined fused kernel (depth-1). Each wave owns 16-edge chunks
// (chunk = gw + k*STRIDE). Per chunk: convert raw -> sfrag; issue next
// chunk's gather (completes under MFMA); GEMM1 transposed (acc1 = W1frag *
// sfrag); relu+bias+bf16 in regs; GEMM2 transposed (acc2 = W2frag * hfrag);
// epilogue 8 float4 stores per lane. Weights+biases in LDS -> MFMA loop has
// zero vmem ops, so in-flight gathers are never drained early by vmcnt.
// BFX: gather from bf16 x-copy (half bytes, L3-resident); else fp32 x.
template <bool BFX>
__global__ __launch_bounds__(THREADS, 3) void gin_kernel(
        const float* __restrict__ x, const unsigned short* __restrict__ xb,
        const int* __restrict__ ei,
        const float* __restrict__ b1, const float* __restrict__ b2,
        const unsigned short* __restrict__ wsw,
        float* __restrict__ out) {
    extern __shared__ char smem[];
    const int tid = threadIdx.x;
    const int lane = tid & 63, q = lane >> 4, col = lane & 15;

    const int gw = blockIdx.x * 12 + (tid >> 6);  // < 3072 <= NCHUNK: valid
    int ch = gw;

    float4  rawf[BFX ? 1 : 16];   // unused variant folds away
    shortx8 rawb[BFX ? 8 : 1];

    auto gather = [&](int na, int nb) {
        if constexpr (BFX) {
            // lane (q,col): bf16 elems [ks*32+q*8 .. +7] of both rows (16B each)
            const shortx8* pa = (const shortx8*)xb + (size_t)na * 16 + q;
            const shortx8* pb = (const shortx8*)xb + (size_t)nb * 16 + q;
            #pragma unroll
            for (int ks = 0; ks < 4; ++ks) {
                rawb[ks*2+0] = pa[ks*4];
                rawb[ks*2+1] = pb[ks*4];
            }
        } else {
            const float* pa = x + (size_t)na * DIN + q * 8;
            const float* pb = x + (size_t)nb * DIN + q * 8;
            #pragma unroll
            for (int ks = 0; ks < 4; ++ks) {
                rawf[ks*4+0] = *(const float4*)(pa + ks*32);
                rawf[ks*4+1] = *(const float4*)(pa + ks*32 + 4);
                rawf[ks*4+2] = *(const float4*)(pb + ks*32);
                rawf[ks*4+3] = *(const float4*)(pb + ks*32 + 4);
            }
        }
    };

    // ---- prologue ----
    const int e0 = ch * 16 + col;
    const int na0 = ei[e0];
    const int nb0 = ei[EDGES + e0];

    // weights -> LDS (131072 B = 8192 float4)
    {
        const float4* gsrc = (const float4*)wsw;
        for (int idx = tid; idx < 8192; idx += THREADS) {
            float4 v = gsrc[idx];
            *(float4*)(smem + (size_t)idx * 16) = v;
        }
        if (tid < 384) {
            float v = (tid < 256) ? b1[tid] : b2[tid - 256];
            *(float*)(smem + B1_OFF + tid * 4) = v;
        }
    }

    gather(na0, nb0);

    int naN, nbN;
    {
        const int e1 = (ch + STRIDE) * 16 + col;
        naN = ei[e1];
        nbN = ei[EDGES + e1];
    }
    __syncthreads();   // weights ready; no barriers after this point

    const shortx8* w1l = (const shortx8*)smem + lane;
    const shortx4* w2l = (const shortx4*)(smem + W2_OFF) + lane;
    const floatx4* b1l = (const floatx4*)(smem + B1_OFF) + q;
    const floatx4* b2l = (const floatx4*)(smem + B2_OFF) + q;

    for (;;) {
        // convert raw -> sfrag (B-frag: n=edge=col, k=ks*32+q*8+j)
        shortx8 sfrag[4];
        if constexpr (BFX) {
            #pragma unroll
            for (int ks = 0; ks < 4; ++ks) {
                union { shortx8 s8; __hip_bfloat162 h[4]; } A, B, S;
                A.s8 = rawb[ks*2]; B.s8 = rawb[ks*2+1];
                #pragma unroll
                for (int j = 0; j < 4; ++j) {
                    float2 fa = __bfloat1622float2(A.h[j]);
                    float2 fb = __bfloat1622float2(B.h[j]);
                    S.h[j] = __float22bfloat162_rn(make_float2(fa.x + fb.x, fa.y + fb.y));
                }
                sfrag[ks] = S.s8;
            }
        } else {
            #pragma unroll
            for (int ks = 0; ks < 4; ++ks) {
                float4 u0 = rawf[ks*4+0], u1 = rawf[ks*4+1];
                float4 v0 = rawf[ks*4+2], v1 = rawf[ks*4+3];
                union { shortx8 s8; __hip_bfloat162 b[4]; } pk;
                pk.b[0] = __float22bfloat162_rn(make_float2(u0.x+v0.x, u0.y+v0.y));
                pk.b[1] = __float22bfloat162_rn(make_float2(u0.z+v0.z, u0.w+v0.w));
                pk.b[2] = __float22bfloat162_rn(make_float2(u1.x+v1.x, u1.y+v1.y));
                pk.b[3] = __float22bfloat162_rn(make_float2(u1.z+v1.z, u1.w+v1.w));
                sfrag[ks] = pk.s8;
            }
        }

        // issue next chunk's gather NOW; it completes under the MFMA phase
        const int chN = ch + STRIDE;
        const bool haveN = (chN < NCHUNK);
        if (haveN) {
            gather(naN, nbN);
            const int ch2 = chN + STRIDE;
            if (ch2 < NCHUNK) {
                const int e2 = ch2 * 16 + col;
                naN = ei[e2];
                nbN = ei[EDGES + e2];
            }
        }

        // ---- MFMA phase: LDS-only operand traffic ----
        floatx4 acc2[8];
        #pragma unroll
        for (int ot = 0; ot < 8; ++ot) acc2[ot] = b2l[ot*4];   // bias init

        #pragma unroll 1
        for (int t = 0; t < 16; ++t) {
            shortx8 a1[4];
            #pragma unroll
            for (int ks = 0; ks < 4; ++ks) a1[ks] = w1l[(t*4+ks)*64];
            floatx4 acc1 = b1l[t*4];                            // bias init
            #pragma unroll
            for (int ks = 0; ks < 4; ++ks)
                acc1 = __builtin_amdgcn_mfma_f32_16x16x32_bf16(a1[ks], sfrag[ks], acc1, 0, 0, 0);
            union { shortx4 s4; __hip_bfloat162 b[2]; } pk;
            pk.b[0] = __float22bfloat162_rn(make_float2(fmaxf(acc1[0], 0.f), fmaxf(acc1[1], 0.f)));
            pk.b[1] = __float22bfloat162_rn(make_float2(fmaxf(acc1[2], 0.f), fmaxf(acc1[3], 0.f)));
            const shortx4 hf = pk.s4;
            #pragma unroll
            for (int ot = 0; ot < 8; ++ot) {
                shortx4 wb = w2l[(t*8+ot)*64];
                // swapped operands: D^T, C-layout col=edge, row=outcol-frag
                acc2[ot] = __builtin_amdgcn_mfma_f32_16x16x16bf16_1k(wb, hf, acc2[ot], 0, 0, 0);
            }
        }

        // ---- epilogue: out[edge=ch*16+col][ot*16 + q*4 + r] = 0.5*acc2 ----
        {
            float* op = out + (size_t)(ch * 16 + col) * DOUT + q * 4;
            #pragma unroll
            for (int ot = 0; ot < 8; ++ot) {
                floatx4 v = acc2[ot] * 0.5f;
                *(floatx4*)(op + ot * 16) = v;
            }
        }

        if (!haveN) break;
        ch = chN;
    }
}

extern "C" void kernel_launch(void* const* d_in, const int* in_sizes, int n_in,
                              void* d_out, int out_size, void* d_ws, size_t ws_size,
                              hipStream_t stream) {
    const float* x  = (const float*)d_in[0];
    const int*   ei = (const int*)d_in[1];     // edge_index as int32 per harness
    const float* W1 = (const float*)d_in[2];
    const float* b1 = (const float*)d_in[3];
    const float* W2 = (const float*)d_in[4];
    const float* b2 = (const float*)d_in[5];
    unsigned short* ws = (unsigned short*)d_ws;

    static bool attr_done = false;
    if (!attr_done) {
        (void)hipFuncSetAttribute((const void*)gin_kernel<true>,
                                  hipFuncAttributeMaxDynamicSharedMemorySize,
                                  LDS_BYTES);
        (void)hipFuncSetAttribute((const void*)gin_kernel<false>,
                                  hipFuncAttributeMaxDynamicSharedMemorySize,
                                  LDS_BYTES);
        attr_done = true;
    }

    prep_kernel<<<48, 256, 0, stream>>>(W1, W2, ws);
    if (ws_size >= WS_BYTES_NEEDED) {
        unsigned short* xb = ws + XB_OFF_SHORTS;
        prep_x<<<2048, 256, 0, stream>>>(x, xb);
        gin_kernel<true><<<NBLK, THREADS, LDS_BYTES, stream>>>(
            x, xb, ei, b1, b2, ws, (float*)d_out);
    } else {
        gin_kernel<false><<<NBLK, THREADS, LDS_BYTES, stream>>>(
            x, nullptr, ei, b1, b2, ws, (float*)d_out);
    }
}